// Round 1
// 115.059 us; speedup vs baseline: 1.0295x; 1.0295x over previous
//
#include <hip/hip_runtime.h>
#include <stdint.h>
#include <limits.h>

// Flip to 0 if validation shows wrong RNG path (legacy non-partitionable threefry).
#define THREEFRY_PARTITIONABLE 1

#define NTK   1024           // threads per block: 16 waves, one block per row
#define NWAVE (NTK/64)       // 16
#define NBUCK 4096           // histogram buckets (monotone float key >> 20)
#define BPT   (NBUCK/NTK)    // buckets per thread in the block scan (4)
#define CAP   2048           // per-row candidate cap (LDS); expected C ~250-400
#define KMAX  512            // max supported top_k

#if __has_builtin(__builtin_amdgcn_exp2f)
#define FAST_EXP2(x) __builtin_amdgcn_exp2f(x)
#else
#define FAST_EXP2(x) exp2f(x)
#endif

__device__ __forceinline__ uint32_t rotl32(uint32_t v, int r) {
  return (v << r) | (v >> (32 - r));
}
__device__ __forceinline__ void tfround(uint32_t& x0, uint32_t& x1, int r) {
  x0 += x1; x1 = rotl32(x1, r); x1 ^= x0;
}
// JAX threefry2x32: 20 rounds, rotations [13,15,26,6]/[17,29,16,24]
__device__ __forceinline__ void threefry2x32(uint32_t k0, uint32_t k1,
                                             uint32_t x0, uint32_t x1,
                                             uint32_t& o0, uint32_t& o1) {
  uint32_t k2 = k0 ^ k1 ^ 0x1BD11BDAu;
  x0 += k0; x1 += k1;
  tfround(x0,x1,13); tfround(x0,x1,15); tfround(x0,x1,26); tfround(x0,x1,6);
  x0 += k1; x1 += k2 + 1u;
  tfround(x0,x1,17); tfround(x0,x1,29); tfround(x0,x1,16); tfround(x0,x1,24);
  x0 += k2; x1 += k0 + 2u;
  tfround(x0,x1,13); tfround(x0,x1,15); tfround(x0,x1,26); tfround(x0,x1,6);
  x0 += k0; x1 += k1 + 3u;
  tfround(x0,x1,17); tfround(x0,x1,29); tfround(x0,x1,16); tfround(x0,x1,24);
  x0 += k1; x1 += k2 + 4u;
  tfround(x0,x1,13); tfround(x0,x1,15); tfround(x0,x1,26); tfround(x0,x1,6);
  x0 += k2; x1 += k0 + 5u;
  o0 = x0; o1 = x1;
}
// Exponential noise for flat element i: jax.random.exponential(fold_in(key(0),1))
__device__ __forceinline__ float jax_noise(uint32_t kn0, uint32_t kn1,
                                           unsigned long long i,
                                           unsigned long long total) {
  uint32_t o0, o1, bits;
#if THREEFRY_PARTITIONABLE
  threefry2x32(kn0, kn1, (uint32_t)(i >> 32), (uint32_t)(i & 0xFFFFFFFFull), o0, o1);
  bits = o0 ^ o1;
#else
  unsigned long long H = total >> 1;
  if (i < H) { threefry2x32(kn0, kn1, (uint32_t)i, (uint32_t)(i + H), o0, o1); bits = o0; }
  else       { threefry2x32(kn0, kn1, (uint32_t)(i - H), (uint32_t)i, o0, o1); bits = o1; }
#endif
  float u = __uint_as_float((bits >> 9) | 0x3f800000u) - 1.0f;  // [0,1)
  float e = -log1pf(-u);
  return fmaxf(e, 1e-10f);
}
// Monotone float -> uint32 key (total order preserving)
__device__ __forceinline__ uint32_t fkey(float f) {
  uint32_t u = __float_as_uint(f);
  return u ^ ((u >> 31) ? 0xFFFFFFFFu : 0x80000000u);
}
// Smallest float whose key >= keyT (bucket floor). keyT==0 -> -inf (emit all).
__device__ __forceinline__ float unfkey_floor(uint32_t keyT) {
  if (keyT == 0u) return -INFINITY;
  return __uint_as_float((keyT & 0x80000000u) ? (keyT ^ 0x80000000u) : ~keyT);
}
__device__ __forceinline__ int clamp_k(int k) {
  if (k < 1) k = 1;
  if (k > KMAX) k = KMAX;
  return k;
}

// Block-parallel suffix-scan of hist -> bucket of the rank-k largest entry.
// beta_sh must be pre-zeroed; hist filled and barrier'd before the call.
// Conservative when hist holds a subset (undercount -> lower bucket).
__device__ __forceinline__ void block_kth_bucket(uint32_t* hist, uint32_t* wtot,
                                                 int* beta_sh, int k,
                                                 int tid, int lane, int wave) {
  const int base = tid * BPT;
  uint32_t tsum = 0;
#pragma unroll
  for (int j = 0; j < BPT; j++) tsum += hist[base + j];
  uint32_t incl = tsum;                    // inclusive suffix over lanes >= lane
  for (int off = 1; off < 64; off <<= 1) {
    uint32_t v = __shfl_down(incl, off);
    if (lane + off < 64) incl += v;
  }
  if (lane == 0) wtot[wave] = incl;
  __syncthreads();
  uint32_t above = incl - tsum;            // threads strictly above (same wave)
  for (int w = wave + 1; w < NWAVE; w++) above += wtot[w];
  if (above < (uint32_t)k && above + tsum >= (uint32_t)k) {
    uint32_t run = above;
    for (int j = BPT - 1; j >= 0; j--) {
      run += hist[base + j];
      if (run >= (uint32_t)k) { *beta_sh = base + j; break; }
    }
  }
  __syncthreads();
}

// ========= Fused per-row sampler: one block per row, no workspace =========
// Phase 1 (stream): single pass over the row, 4-deep float4 loads. Per thread:
// branchless top-2 (value,idx) on RAW logit bits (T>0, IEEE division monotone),
// plus dsum accumulation 2^(l*log2e/T) in 4 rotating f32 accumulators -> f64
// wave fold. Histogram of thread top-2 values -> conservative kth bucket
// (subset undercount => bucket <= true kth bucket => emission superset).
// Phase 2 (in-block finalize): emit candidates >= bucket floor into LDS
// (registers for <=1 hit, strided L2 rescan for >=2 hits), exact p for the
// ~300 survivors, exact (p desc, idx asc) rank, top-p prefix, threefry
// Gumbel-style noise, argmax. Identical arithmetic to the validated 2-kernel
// path: raw f64 sum rescaled once by 2^(-mg*log2e/T), m = mg/T, expf/ieee-div
// for survivors, same tie rules and RNG.
__global__ __launch_bounds__(NTK, 1)
void sampler_fused(const float* __restrict__ logits,
                   const float* __restrict__ temps,
                   const int* __restrict__ topk_ptr,
                   int* __restrict__ out,
                   int B, int V) {
  const int b = blockIdx.x;
  const int tid = threadIdx.x, lane = tid & 63, wave = tid >> 6;

  __shared__ uint32_t hist[NBUCK];
  __shared__ float cv[CAP];
  __shared__ int   ci[CAP];
  __shared__ float cp[CAP];
  __shared__ float sv[KMAX];
  __shared__ int   si[KMAX];
  __shared__ float sc[KMAX];
  __shared__ float wm[NWAVE];
  __shared__ double wsum[NWAVE];
  __shared__ uint32_t wtot[NWAVE];
  __shared__ int beta_sh, cnum_sh, L_sh;
  __shared__ float m_sh, D_sh;

  if (tid == 0) { beta_sh = 0; cnum_sh = 0; }
  for (int i = tid; i < NBUCK; i += NTK) hist[i] = 0;
  __syncthreads();                         // hist zeroed before any atomics

  const float T = temps[b];
  const float cf = (float)(1.4426950408889634 / (double)T);  // log2e / T
  const int k = clamp_k(*topk_ptr);
  const float* row = logits + (size_t)b * (size_t)V;
  const int n4 = ((V & 3) == 0) ? (V >> 2) : 0;   // float4 path only if aligned
  const float4* row4 = (const float4*)row;

  // per-thread state: branchless top-2 + exp2 accumulators
  float v0 = -INFINITY, v1 = -INFINITY;
  int   i0 = 0, i1 = 0;
  float a0 = 0.f, a1 = 0.f, a2 = 0.f, a3 = 0.f;

  auto proc = [&](float f, int idx) {
    bool gt0 = f > v0;
    bool gt1 = f > v1;
    float nv1 = gt0 ? v0 : (gt1 ? f : v1);
    int   ni1 = gt0 ? i0 : (gt1 ? idx : i1);
    v1 = nv1; i1 = ni1;
    v0 = gt0 ? f : v0;
    i0 = gt0 ? idx : i0;
  };
  auto proc4 = [&](float4 f, int vb, float& a) {
    proc(f.x, vb); proc(f.y, vb + 1); proc(f.z, vb + 2); proc(f.w, vb + 3);
    a += (FAST_EXP2(f.x * cf) + FAST_EXP2(f.y * cf))
       + (FAST_EXP2(f.z * cf) + FAST_EXP2(f.w * cf));
  };

  // ---- streaming pass: 4 independent float4 loads in flight per wave ----
  int i = tid;
  for (; i + 3 * NTK < n4; i += 4 * NTK) {
    float4 fa = row4[i];
    float4 fb = row4[i + NTK];
    float4 fc = row4[i + 2 * NTK];
    float4 fd = row4[i + 3 * NTK];
    proc4(fa, i * 4, a0);
    proc4(fb, (i + NTK) * 4, a1);
    proc4(fc, (i + 2 * NTK) * 4, a2);
    proc4(fd, (i + 3 * NTK) * 4, a3);
  }
  for (; i < n4; i += NTK) {
    float4 fa = row4[i];
    proc4(fa, i * 4, a0);
  }
  for (int v = n4 * 4 + tid; v < V; v += NTK) {
    float f = row[v];
    proc(f, v);
    a0 += FAST_EXP2(f * cf);
  }

  // wave reductions: block max + raw f64 exp2 sum
  float bm = v0;
  for (int off = 32; off; off >>= 1)
    bm = fmaxf(bm, __shfl_down(bm, off));
  if (lane == 0) wm[wave] = bm;

  double ds = ((double)a0 + (double)a1) + ((double)a2 + (double)a3);
  for (int off = 32; off; off >>= 1)
    ds += __shfl_down(ds, off);
  if (lane == 0) wsum[wave] = ds;

  // histogram thread top-2 (subset of row -> conservative threshold, tighter
  // than top-1-only: kth of 2048 maxes is closer to the true kth element)
  if (v0 != -INFINITY) atomicAdd(&hist[fkey(v0) >> 20], 1u);
  if (v1 != -INFINITY) atomicAdd(&hist[fkey(v1) >> 20], 1u);
  __syncthreads();                         // wm + wsum + hist atomics

  if (tid == 0) {
    float mg = wm[0];
#pragma unroll
    for (int w = 1; w < NWAVE; w++) mg = fmaxf(mg, wm[w]);
    double t = 0.0;
    for (int w = 0; w < NWAVE; w++) t += wsum[w];
    const double cd = 1.4426950408889634 / (double)T;
    D_sh = (float)(t * exp2(-(double)mg * cd));   // single f64 rescale per row
    m_sh = mg / T;     // == max over fl(l/T) (monotone IEEE division)
  }

  block_kth_bucket(hist, wtot, &beta_sh, k, tid, lane, wave);

  // ---- emit: registers for the common case, rescan only on >=2 hits ----
  // Emission set = ALL elements >= fT (exact), a superset of the row top-k.
  const float fT = unfkey_floor((uint32_t)beta_sh << 20);
  if (v1 >= fT) {
    // rare (~few threads/block): >=2 elements above threshold -> exact rescan
    // of this thread's strided slice (L2-warm, ~500B per rescanning thread)
    for (int i2 = tid; i2 < n4; i2 += NTK) {
      float4 f = row4[i2];
      const int vb = i2 * 4;
      if (f.x >= fT) { int p = atomicAdd(&cnum_sh, 1); if (p < CAP) { cv[p] = f.x; ci[p] = vb; } }
      if (f.y >= fT) { int p = atomicAdd(&cnum_sh, 1); if (p < CAP) { cv[p] = f.y; ci[p] = vb + 1; } }
      if (f.z >= fT) { int p = atomicAdd(&cnum_sh, 1); if (p < CAP) { cv[p] = f.z; ci[p] = vb + 2; } }
      if (f.w >= fT) { int p = atomicAdd(&cnum_sh, 1); if (p < CAP) { cv[p] = f.w; ci[p] = vb + 3; } }
    }
    for (int v = n4 * 4 + tid; v < V; v += NTK) {
      float f = row[v];
      if (f >= fT) { int p = atomicAdd(&cnum_sh, 1); if (p < CAP) { cv[p] = f; ci[p] = v; } }
    }
  } else if (v0 >= fT) {
    int p = atomicAdd(&cnum_sh, 1);
    if (p < CAP) { cv[p] = v0; ci[p] = i0; }
  }
  __syncthreads();

  const int C = min(cnum_sh, CAP);
  const float m = m_sh, D = D_sh;
  // exact-path p for the ~300 survivors: real IEEE div + libm expf
  for (int t = tid; t < C; t += NTK)
    cp[t] = expf(cv[t] / T - m) / D;
  __syncthreads();

  // exact ranking: (p desc, idx asc) — JAX top_k / stable argsort tie rule
  for (int t = tid; t < C; t += NTK) {
    float pi = cp[t];
    int   ii = ci[t];
    int r = 0;
    for (int j = 0; j < C; j++) {
      float pj = cp[j];
      r += (pj > pi) || (pj == pi && ci[j] < ii);
    }
    if (r < k) { sv[r] = pi; si[r] = ii; }
  }
  __syncthreads();

  // top-p: sequential fp32 cumsum, keep prefix (first always kept)
  const int kk = (k < C) ? k : C;
  if (tid == 0) {
    float cum = 0.f;
    int L = 1;
    for (int j = 0; j < kk; j++) {
      cum += sv[j];
      if (j == 0) continue;
      if (cum <= 0.9f) L = j + 1; else break;
    }
    L_sh = L;
  }
  __syncthreads();

  const int L = L_sh;
  {
    uint32_t kn0, kn1;
    threefry2x32(0u, 0u, 0u, 1u, kn0, kn1);   // fold_in(key(0), 1)
    unsigned long long total = (unsigned long long)B * (unsigned long long)V;
    for (int j = tid; j < L; j += NTK) {
      unsigned long long flat = (unsigned long long)b * (unsigned long long)V
                              + (unsigned long long)si[j];
      sc[j] = sv[j] / jax_noise(kn0, kn1, flat, total);
    }
  }
  __syncthreads();

  if (tid == 0) {
    float bs = -1.0f;
    int   bi = INT_MAX;
    for (int j = 0; j < L; j++) {
      if (sc[j] > bs || (sc[j] == bs && si[j] < bi)) { bs = sc[j]; bi = si[j]; }
    }
    out[b] = bi;
  }
}

extern "C" void kernel_launch(void* const* d_in, const int* in_sizes, int n_in,
                              void* d_out, int out_size, void* d_ws, size_t ws_size,
                              hipStream_t stream) {
  const float* logits = (const float*)d_in[0];
  const float* temps  = (const float*)d_in[1];
  const int*   topk   = (const int*)d_in[2];
  int* out = (int*)d_out;

  int B = in_sizes[1];
  int V = in_sizes[0] / B;

  // One block per row; no workspace, single launch.
  sampler_fused<<<dim3(B), dim3(NTK), 0, stream>>>(logits, temps, topk, out, B, V);
}

// Round 2
// 109.912 us; speedup vs baseline: 1.0777x; 1.0468x over previous
//
#include <hip/hip_runtime.h>
#include <stdint.h>
#include <limits.h>

// Flip to 0 if validation shows wrong RNG path (legacy non-partitionable threefry).
#define THREEFRY_PARTITIONABLE 1

#define NTK   1024           // threads per block: 16 waves, one block per row
#define NWAVE (NTK/64)       // 16
#define NBUCK 4096           // histogram buckets (monotone float key >> 20)
#define BPT   (NBUCK/NTK)    // buckets per thread in the block scan (4)
#define CAP   2048           // per-row candidate cap (LDS); expected C ~150-400
#define KMAX  512            // max supported top_k

#if __has_builtin(__builtin_amdgcn_exp2f)
#define FAST_EXP2(x) __builtin_amdgcn_exp2f(x)
#else
#define FAST_EXP2(x) exp2f(x)
#endif

__device__ __forceinline__ uint32_t rotl32(uint32_t v, int r) {
  return (v << r) | (v >> (32 - r));
}
__device__ __forceinline__ void tfround(uint32_t& x0, uint32_t& x1, int r) {
  x0 += x1; x1 = rotl32(x1, r); x1 ^= x0;
}
// JAX threefry2x32: 20 rounds, rotations [13,15,26,6]/[17,29,16,24]
__device__ __forceinline__ void threefry2x32(uint32_t k0, uint32_t k1,
                                             uint32_t x0, uint32_t x1,
                                             uint32_t& o0, uint32_t& o1) {
  uint32_t k2 = k0 ^ k1 ^ 0x1BD11BDAu;
  x0 += k0; x1 += k1;
  tfround(x0,x1,13); tfround(x0,x1,15); tfround(x0,x1,26); tfround(x0,x1,6);
  x0 += k1; x1 += k2 + 1u;
  tfround(x0,x1,17); tfround(x0,x1,29); tfround(x0,x1,16); tfround(x0,x1,24);
  x0 += k2; x1 += k0 + 2u;
  tfround(x0,x1,13); tfround(x0,x1,15); tfround(x0,x1,26); tfround(x0,x1,6);
  x0 += k0; x1 += k1 + 3u;
  tfround(x0,x1,17); tfround(x0,x1,29); tfround(x0,x1,16); tfround(x0,x1,24);
  x0 += k1; x1 += k2 + 4u;
  tfround(x0,x1,13); tfround(x0,x1,15); tfround(x0,x1,26); tfround(x0,x1,6);
  x0 += k2; x1 += k0 + 5u;
  o0 = x0; o1 = x1;
}
// Exponential noise for flat element i: jax.random.exponential(fold_in(key(0),1))
__device__ __forceinline__ float jax_noise(uint32_t kn0, uint32_t kn1,
                                           unsigned long long i,
                                           unsigned long long total) {
  uint32_t o0, o1, bits;
#if THREEFRY_PARTITIONABLE
  threefry2x32(kn0, kn1, (uint32_t)(i >> 32), (uint32_t)(i & 0xFFFFFFFFull), o0, o1);
  bits = o0 ^ o1;
#else
  unsigned long long H = total >> 1;
  if (i < H) { threefry2x32(kn0, kn1, (uint32_t)i, (uint32_t)(i + H), o0, o1); bits = o0; }
  else       { threefry2x32(kn0, kn1, (uint32_t)(i - H), (uint32_t)i, o0, o1); bits = o1; }
#endif
  float u = __uint_as_float((bits >> 9) | 0x3f800000u) - 1.0f;  // [0,1)
  float e = -log1pf(-u);
  return fmaxf(e, 1e-10f);
}
// Monotone float -> uint32 key (total order preserving)
__device__ __forceinline__ uint32_t fkey(float f) {
  uint32_t u = __float_as_uint(f);
  return u ^ ((u >> 31) ? 0xFFFFFFFFu : 0x80000000u);
}
// Smallest float whose key >= keyT (bucket floor). keyT==0 -> -inf (emit all).
__device__ __forceinline__ float unfkey_floor(uint32_t keyT) {
  if (keyT == 0u) return -INFINITY;
  return __uint_as_float((keyT & 0x80000000u) ? (keyT ^ 0x80000000u) : ~keyT);
}
__device__ __forceinline__ int clamp_k(int k) {
  if (k < 1) k = 1;
  if (k > KMAX) k = KMAX;
  return k;
}

// Block-parallel suffix-scan of hist -> bucket of the rank-k largest entry.
// beta_sh must be pre-zeroed; hist filled and barrier'd before the call.
// Conservative when hist holds a subset (undercount -> lower bucket).
__device__ __forceinline__ void block_kth_bucket(uint32_t* hist, uint32_t* wtot,
                                                 int* beta_sh, int k,
                                                 int tid, int lane, int wave) {
  const int base = tid * BPT;
  uint32_t tsum = 0;
#pragma unroll
  for (int j = 0; j < BPT; j++) tsum += hist[base + j];
  uint32_t incl = tsum;                    // inclusive suffix over lanes >= lane
  for (int off = 1; off < 64; off <<= 1) {
    uint32_t v = __shfl_down(incl, off);
    if (lane + off < 64) incl += v;
  }
  if (lane == 0) wtot[wave] = incl;
  __syncthreads();
  uint32_t above = incl - tsum;            // threads strictly above (same wave)
  for (int w = wave + 1; w < NWAVE; w++) above += wtot[w];
  if (above < (uint32_t)k && above + tsum >= (uint32_t)k) {
    uint32_t run = above;
    for (int j = BPT - 1; j >= 0; j--) {
      run += hist[base + j];
      if (run >= (uint32_t)k) { *beta_sh = base + j; break; }
    }
  }
  __syncthreads();
}

// ========= Fused per-row sampler: one block per row, no workspace =========
// Phase 1 (stream): single pass over the row, 8-deep float4 loads. Per thread:
// branchless top-3 (v0,i0 / v1,i1 / v2 value-only) on RAW logit bits (T>0,
// IEEE division monotone), plus dsum accumulation 2^(l*log2e/T) in 4 rotating
// f32 accumulators (group g -> acc g&3, identical association to the
// validated kernel -> D bit-identical) -> f64 wave fold. Histogram of thread
// top-2 values -> conservative kth bucket (subset undercount => bucket <=
// true kth bucket => emission superset).
// Phase 2 (in-block finalize): emit candidates >= bucket floor. v0/v1 emitted
// straight from registers; a 4-deep-pipelined rescan only when v2 >= fT
// (expected ~2-3 threads/block). Exact p for ~300 survivors, exact
// (p desc, idx asc) rank, serial-order top-p cumsum (chunk-prefetched LDS
// reads, same fp association), threefry noise computed speculatively for all
// j < kk in parallel with the cumsum, exact wave-parallel argmax.
__global__ __launch_bounds__(NTK, 1)
void sampler_fused(const float* __restrict__ logits,
                   const float* __restrict__ temps,
                   const int* __restrict__ topk_ptr,
                   int* __restrict__ out,
                   int B, int V) {
  const int b = blockIdx.x;
  const int tid = threadIdx.x, lane = tid & 63, wave = tid >> 6;

  __shared__ uint32_t hist[NBUCK];
  __shared__ float cv[CAP];
  __shared__ int   ci[CAP];
  __shared__ float cp[CAP];
  __shared__ float sv[KMAX];
  __shared__ int   si[KMAX];   // directly after sv: cumsum chunk over-read lands here (benign)
  __shared__ float sc[KMAX];
  __shared__ float wm[NWAVE];
  __shared__ double wsum[NWAVE];
  __shared__ uint32_t wtot[NWAVE];
  __shared__ int beta_sh, cnum_sh, L_sh;
  __shared__ float m_sh, D_sh;

  if (tid == 0) { beta_sh = 0; cnum_sh = 0; }
  for (int i = tid; i < NBUCK; i += NTK) hist[i] = 0;
  __syncthreads();                         // hist zeroed before any atomics

  const float T = temps[b];
  const float cf = (float)(1.4426950408889634 / (double)T);  // log2e / T
  const int k = clamp_k(*topk_ptr);
  const float* row = logits + (size_t)b * (size_t)V;
  const int n4 = ((V & 3) == 0) ? (V >> 2) : 0;   // float4 path only if aligned
  const float4* row4 = (const float4*)row;

  // per-thread state: branchless top-3 (3rd is value-only) + exp2 accumulators
  float v0 = -INFINITY, v1 = -INFINITY, v2 = -INFINITY;
  int   i0 = 0, i1 = 0;
  float a0 = 0.f, a1 = 0.f, a2 = 0.f, a3 = 0.f;

  auto proc = [&](float f, int idx) {
    bool gt0 = f > v0;
    bool gt1 = f > v1;
    bool gt2 = f > v2;
    float nv2 = gt1 ? v1 : (gt2 ? f : v2);
    float nv1 = gt0 ? v0 : (gt1 ? f : v1);
    int   ni1 = gt0 ? i0 : (gt1 ? idx : i1);
    v2 = nv2;
    v1 = nv1; i1 = ni1;
    v0 = gt0 ? f : v0;
    i0 = gt0 ? idx : i0;
  };
  auto proc4 = [&](float4 f, int vb, float& a) {
    proc(f.x, vb); proc(f.y, vb + 1); proc(f.z, vb + 2); proc(f.w, vb + 3);
    a += (FAST_EXP2(f.x * cf) + FAST_EXP2(f.y * cf))
       + (FAST_EXP2(f.z * cf) + FAST_EXP2(f.w * cf));
  };

  // ---- streaming pass: 8 independent float4 loads in flight per wave ----
  // accumulator mapping: load-group g -> acc (g & 3)  [bit-identical to prior]
  int i = tid;
  for (; i + 7 * NTK < n4; i += 8 * NTK) {
    float4 f0 = row4[i];
    float4 f1 = row4[i + NTK];
    float4 f2 = row4[i + 2 * NTK];
    float4 f3 = row4[i + 3 * NTK];
    float4 f4 = row4[i + 4 * NTK];
    float4 f5 = row4[i + 5 * NTK];
    float4 f6 = row4[i + 6 * NTK];
    float4 f7 = row4[i + 7 * NTK];
    proc4(f0, i * 4, a0);
    proc4(f1, (i + NTK) * 4, a1);
    proc4(f2, (i + 2 * NTK) * 4, a2);
    proc4(f3, (i + 3 * NTK) * 4, a3);
    proc4(f4, (i + 4 * NTK) * 4, a0);
    proc4(f5, (i + 5 * NTK) * 4, a1);
    proc4(f6, (i + 6 * NTK) * 4, a2);
    proc4(f7, (i + 7 * NTK) * 4, a3);
  }
  for (; i + 3 * NTK < n4; i += 4 * NTK) {
    float4 fa = row4[i];
    float4 fb = row4[i + NTK];
    float4 fc = row4[i + 2 * NTK];
    float4 fd = row4[i + 3 * NTK];
    proc4(fa, i * 4, a0);
    proc4(fb, (i + NTK) * 4, a1);
    proc4(fc, (i + 2 * NTK) * 4, a2);
    proc4(fd, (i + 3 * NTK) * 4, a3);
  }
  for (; i < n4; i += NTK) {
    float4 fa = row4[i];
    proc4(fa, i * 4, a0);
  }
  for (int v = n4 * 4 + tid; v < V; v += NTK) {
    float f = row[v];
    proc(f, v);
    a0 += FAST_EXP2(f * cf);
  }

  // wave reductions: block max + raw f64 exp2 sum
  float bm = v0;
  for (int off = 32; off; off >>= 1)
    bm = fmaxf(bm, __shfl_down(bm, off));
  if (lane == 0) wm[wave] = bm;

  double ds = ((double)a0 + (double)a1) + ((double)a2 + (double)a3);
  for (int off = 32; off; off >>= 1)
    ds += __shfl_down(ds, off);
  if (lane == 0) wsum[wave] = ds;

  // histogram thread top-2 (subset of row -> conservative threshold)
  if (v0 != -INFINITY) atomicAdd(&hist[fkey(v0) >> 20], 1u);
  if (v1 != -INFINITY) atomicAdd(&hist[fkey(v1) >> 20], 1u);
  __syncthreads();                         // wm + wsum + hist atomics

  if (tid == 0) {
    float mg = wm[0];
#pragma unroll
    for (int w = 1; w < NWAVE; w++) mg = fmaxf(mg, wm[w]);
    double t = 0.0;
    for (int w = 0; w < NWAVE; w++) t += wsum[w];   // serial order: D bit-stable
    const double cd = 1.4426950408889634 / (double)T;
    D_sh = (float)(t * exp2(-(double)mg * cd));   // single f64 rescale per row
    m_sh = mg / T;     // == max over fl(l/T) (monotone IEEE division)
  }

  block_kth_bucket(hist, wtot, &beta_sh, k, tid, lane, wave);

  // ---- emit: registers for <=2 hits; rare 4-deep-pipelined rescan for >=3 ----
  // Emission set = ALL elements >= fT (exact), a superset of the row top-k.
  const float fT = unfkey_floor((uint32_t)beta_sh << 20);
  auto emit1 = [&](float f, int idx) {
    if (f >= fT) {
      int p = atomicAdd(&cnum_sh, 1);
      if (p < CAP) { cv[p] = f; ci[p] = idx; }
    }
  };
  auto emit4 = [&](float4 f, int vb) {
    emit1(f.x, vb); emit1(f.y, vb + 1); emit1(f.z, vb + 2); emit1(f.w, vb + 3);
  };
  if (v2 >= fT) {
    // this thread may hold >=3 elements above threshold -> exact rescan of
    // its strided slice (pipelined 4-deep; L2/L3-warm; ~2-3 threads/block)
    int i2 = tid;
    for (; i2 + 3 * NTK < n4; i2 += 4 * NTK) {
      float4 fa = row4[i2];
      float4 fb = row4[i2 + NTK];
      float4 fc = row4[i2 + 2 * NTK];
      float4 fd = row4[i2 + 3 * NTK];
      emit4(fa, i2 * 4);
      emit4(fb, (i2 + NTK) * 4);
      emit4(fc, (i2 + 2 * NTK) * 4);
      emit4(fd, (i2 + 3 * NTK) * 4);
    }
    for (; i2 < n4; i2 += NTK) {
      float4 fa = row4[i2];
      emit4(fa, i2 * 4);
    }
    for (int v = n4 * 4 + tid; v < V; v += NTK) {
      float f = row[v];
      emit1(f, v);
    }
  } else {
    // common case: top-2 registers carry every element of this thread >= fT
    if (v0 >= fT) { int p = atomicAdd(&cnum_sh, 1); if (p < CAP) { cv[p] = v0; ci[p] = i0; } }
    if (v1 >= fT) { int p = atomicAdd(&cnum_sh, 1); if (p < CAP) { cv[p] = v1; ci[p] = i1; } }
  }
  __syncthreads();

  const int C = min(cnum_sh, CAP);
  const float m = m_sh, D = D_sh;
  // exact-path p for the ~300 survivors: real IEEE div + libm expf
  for (int t = tid; t < C; t += NTK)
    cp[t] = expf(cv[t] / T - m) / D;
  __syncthreads();

  // exact ranking: (p desc, idx asc) — JAX top_k / stable argsort tie rule
  for (int t = tid; t < C; t += NTK) {
    float pi = cp[t];
    int   ii = ci[t];
    int r = 0;
    for (int j = 0; j < C; j++) {
      float pj = cp[j];
      r += (pj > pi) || (pj == pi && ci[j] < ii);
    }
    if (r < k) { sv[r] = pi; si[r] = ii; }
  }
  __syncthreads();

  const int kk = (k < C) ? k : C;

  // (a) speculative noise scores for ALL j < kk (parallel, overlaps cumsum)
  {
    uint32_t kn0, kn1;
    threefry2x32(0u, 0u, 0u, 1u, kn0, kn1);   // fold_in(key(0), 1)
    unsigned long long total = (unsigned long long)B * (unsigned long long)V;
    for (int j = tid; j < kk; j += NTK) {
      unsigned long long flat = (unsigned long long)b * (unsigned long long)V
                              + (unsigned long long)si[j];
      sc[j] = sv[j] / jax_noise(kn0, kn1, flat, total);
    }
  }

  // (b) top-p: serial fp32 cumsum (EXACT left-to-right association, validated),
  // LDS reads chunk-prefetched 8-at-a-time to amortize latency.
  if (tid == 0) {
    float cum = 0.f;
    int L = 1;
    bool stop = false;
    for (int j0 = 0; j0 < kk && !stop; j0 += 8) {
      // over-read past sv[kk) stays inside this block's LDS (spills into si)
      float t0 = sv[j0],     t1 = sv[j0 + 1], t2 = sv[j0 + 2], t3 = sv[j0 + 3];
      float t4 = sv[j0 + 4], t5 = sv[j0 + 5], t6 = sv[j0 + 6], t7 = sv[j0 + 7];
      float tt[8] = {t0, t1, t2, t3, t4, t5, t6, t7};
#pragma unroll
      for (int q = 0; q < 8; q++) {
        int j = j0 + q;
        if (j >= kk) { stop = true; break; }
        cum += tt[q];
        if (j == 0) continue;
        if (cum <= 0.9f) L = j + 1;
        else { stop = true; break; }
      }
    }
    L_sh = L;
  }
  __syncthreads();

  // exact wave-parallel argmax over j < L: total order (score desc, idx asc)
  if (wave == 0) {
    const int L = L_sh;
    float bs = -1.0f;
    int   bi = INT_MAX;
    for (int j = lane; j < L; j += 64) {
      float s = sc[j];
      int   ix = si[j];
      if (s > bs || (s == bs && ix < bi)) { bs = s; bi = ix; }
    }
    for (int off = 32; off; off >>= 1) {
      float os = __shfl_down(bs, off);
      int   oi = __shfl_down(bi, off);
      if (os > bs || (os == bs && oi < bi)) { bs = os; bi = oi; }
    }
    if (lane == 0) out[b] = bi;
  }
}

extern "C" void kernel_launch(void* const* d_in, const int* in_sizes, int n_in,
                              void* d_out, int out_size, void* d_ws, size_t ws_size,
                              hipStream_t stream) {
  const float* logits = (const float*)d_in[0];
  const float* temps  = (const float*)d_in[1];
  const int*   topk   = (const int*)d_in[2];
  int* out = (int*)d_out;

  int B = in_sizes[1];
  int V = in_sizes[0] / B;

  // One block per row; no workspace, single launch.
  sampler_fused<<<dim3(B), dim3(NTK), 0, stream>>>(logits, temps, topk, out, B, V);
}